// Round 2
// baseline (138477.246 us; speedup 1.0000x reference)
//
#include <hip/hip_runtime.h>
#include <hip/hip_bf16.h>

// Persistent cooperative RNN kernel for MI355X (gfx950).
// 256 WGs x 512 threads, 1 WG/CU (~147KB LDS). Each WG owns 4 hidden rows =>
// 16 gate rows of every 4H weight matrix. 5 grid barriers per time step.
// Cross-WG activations move via relaxed agent-scope atomics (coherence-point
// direct) so no cache-invalidating fences are needed and weight slices stay
// hot in each XCD's L2.
// Input/output dtype (f32 vs bf16) is detected at runtime from X's bit
// patterns and the whole body is templated on it.

typedef unsigned short u16t;
typedef unsigned int u32t;

#define TSTEPS 2045
#define NWG 256
#define NTHR 512

// d_ws float offsets
#define CNT_OFF   0      // barrier counter (uint)
#define HENC_OFF  256    // enc h, ping-pong [2][1024]
#define CENC_OFF  2560   // enc c gather [1024]
#define DH_OFF    3840   // head dhx [1024]
#define DD_OFF    5120   // dec h ping-pong [2][1024]
#define SV_OFF    7424   // split-K cls partials [3][64]
#define FV_OFF    7680   // split-K fut partials [3][64]
#define WS_ZERO_N 8192

struct Params {
  const void *X, *eWih, *eWhh, *ebih, *ebhh, *dWih, *dWhh, *dbih, *dbhh,
             *hxW, *hxb, *cxW, *cxb, *fusW, *fusb_g, *futW, *futb_g, *clsW, *clsb_g;
  float* ws;
  void* out;
};

struct SharedMem {
  u16t  FT[64 * 1024];          // fus_W transposed [o][h], bf16 bits (131072 B)
  float xs[2048];               // staged input vector(s) for dots
  float fusb[1024];
  float cls_sl[256], fut_sl[256];   // [o][j]: this WG's 4 columns
  float clsb[64], futb[64], fut_acc[64], dsbuf[64];
  float bias_e[16], bias_d[16], hxb4[4], cxb4[4];
  float g16[16], h4[4], dcx_s[4], encc[4];
  int bail;
  int badcnt;
};

__device__ __forceinline__ float bfu(u16t u){
  union { u32t i; float f; } v; v.i = ((u32t)u) << 16; return v.f;
}
__device__ __forceinline__ u16t bf16bits(float v){
  __hip_bfloat16 b = __float2bfloat16(v);
  union { __hip_bfloat16 b; u16t u; } c; c.b = b; return c.u;
}
template<bool F32>
__device__ __forceinline__ float ldE(const void* p, int i){
  if (F32) return ((const float*)p)[i];
  return bfu(((const u16t*)p)[i]);
}
template<bool F32>
__device__ __forceinline__ void stO(void* p, int i, float v){
  if (F32) ((float*)p)[i] = v;
  else     ((u16t*)p)[i] = bf16bits(v);
}
__device__ __forceinline__ float sigm(float x){ return 1.f / (1.f + __expf(-x)); }
__device__ __forceinline__ float tanhx(float x){
  float e = __expf(-2.f * fabsf(x));
  float t = (1.f - e) / (1.f + e);
  return copysignf(t, x);
}
// Coherence-point (agent scope, relaxed) store/load: visible across XCDs
// without fences.
__device__ __forceinline__ void stg(float* p, float v){
  __hip_atomic_store(p, v, __ATOMIC_RELAXED, __HIP_MEMORY_SCOPE_AGENT);
}
__device__ __forceinline__ float ldgc(const float* p){
  return __hip_atomic_load(p, __ATOMIC_RELAXED, __HIP_MEMORY_SCOPE_AGENT);
}

// Half-wave (32 lanes) dot of weight row (global, f32 or bf16) with f32 x (LDS).
// All 32 lanes return the sum.
template<bool F32>
__device__ __forceinline__ float hw_dot(const void* wbase, long off,
                                        const float* __restrict__ x,
                                        int K, int lane){
  float acc = 0.f;
  if (F32){
    const float* w = (const float*)wbase + off;
    for (int c = lane * 4; c < K; c += 128){
      float4 wv = *(const float4*)(w + c);
      float4 xv = *(const float4*)(x + c);
      acc = fmaf(wv.x, xv.x, acc); acc = fmaf(wv.y, xv.y, acc);
      acc = fmaf(wv.z, xv.z, acc); acc = fmaf(wv.w, xv.w, acc);
    }
  } else {
    const u16t* w = (const u16t*)wbase + off;
    for (int c = lane * 4; c < K; c += 128){
      ushort4 wv = *(const ushort4*)(w + c);
      float4  xv = *(const float4*)(x + c);
      acc = fmaf(bfu(wv.x), xv.x, acc); acc = fmaf(bfu(wv.y), xv.y, acc);
      acc = fmaf(bfu(wv.z), xv.z, acc); acc = fmaf(bfu(wv.w), xv.w, acc);
    }
  }
  #pragma unroll
  for (int o = 16; o; o >>= 1) acc += __shfl_xor(acc, o, 64);
  return acc;
}

// Grid barrier: monotonic coherence-point counter. vmcnt(0) drains this wave's
// stores/atomics before arrival. Anti-hang: ~1ms timeout then finish wrong.
__device__ __forceinline__ void gbar(u32t* cnt, u32t target, int* bail){
  asm volatile("s_waitcnt vmcnt(0)" ::: "memory");
  __syncthreads();
  if (threadIdx.x == 0 && !(*bail)){
    __hip_atomic_fetch_add(cnt, 1u, __ATOMIC_RELAXED, __HIP_MEMORY_SCOPE_AGENT);
    int spins = 0;
    while (__hip_atomic_load(cnt, __ATOMIC_RELAXED, __HIP_MEMORY_SCOPE_AGENT) < target){
      __builtin_amdgcn_s_sleep(1);
      if (++spins > (1 << 15)) { *bail = 1; break; }
    }
  }
  __syncthreads();
}

template<bool F32>
__device__ void run(const Params& p, SharedMem& S){
  const int tid  = threadIdx.x;
  const int w    = blockIdx.x;
  const int hw   = tid >> 5;            // half-wave 0..15 -> one gate row each
  const int lane = tid & 31;
  const long grow = (long)((hw >> 2) * 1024 + 4 * w + (hw & 3));  // gate row
  float* ws = p.ws;
  u32t* cnt = (u32t*)(ws + CNT_OFF);

  // ---------- startup: stage per-WG constants into LDS ----------
  for (int i = tid; i < 64 * 1024; i += NTHR){
    int h = i >> 6, o = i & 63;
    if (F32) S.FT[o * 1024 + h] = bf16bits(((const float*)p.fusW)[i]);
    else     S.FT[o * 1024 + h] = ((const u16t*)p.fusW)[i];
  }
  for (int i = tid; i < 1024; i += NTHR) S.fusb[i] = ldE<F32>(p.fusb_g, i);
  if (tid < 256){
    int o = tid >> 2, j = tid & 3;
    S.cls_sl[tid] = ldE<F32>(p.clsW, o * 1024 + 4 * w + j);
    S.fut_sl[tid] = ldE<F32>(p.futW, o * 1024 + 4 * w + j);
  }
  if (tid < 64){
    S.clsb[tid] = ldE<F32>(p.clsb_g, tid);
    S.futb[tid] = ldE<F32>(p.futb_g, tid);
    S.fut_acc[tid] = 0.f;
  }
  if (tid < 16){
    int gr = (tid >> 2) * 1024 + 4 * w + (tid & 3);
    S.bias_e[tid] = ldE<F32>(p.ebih, gr) + ldE<F32>(p.ebhh, gr);
    S.bias_d[tid] = ldE<F32>(p.dbih, gr) + ldE<F32>(p.dbhh, gr);
  }
  if (tid < 4){
    S.hxb4[tid] = ldE<F32>(p.hxb, 4 * w + tid);
    S.cxb4[tid] = ldE<F32>(p.cxb, 4 * w + tid);
    S.encc[tid] = 0.f;
  }
  __syncthreads();

  u32t target = 0;

  for (int t = 0; t < TSTEPS; ++t){
    // ============ R1: encoder gates ============
    if (tid < 64){
      S.xs[tid] = ldE<F32>(p.X, t * 64 + tid);         // fusion[0:64] = x_t
      float fv = 0.f;
      if (t > 0){
        float f3 = fmaxf(ldgc(ws + FV_OFF + 128 + tid) + S.futb[tid], 0.f);
        fv = (S.fut_acc[tid] + f3) * (1.f / 3.f);      // fut = mean of 3 relus
      }
      S.xs[64 + tid] = fv;                             // fusion[64:128] = fut
      S.fut_acc[tid] = 0.f;
      if (w == 32 && t > 0){                           // ds3 of previous step
        float s = ldgc(ws + SV_OFF + 128 + tid) + S.clsb[tid];
        stO<F32>(p.out, TSTEPS * 64 + ((t - 1) * 3 + 2) * 64 + tid, s);
      }
    }
    {
      const int hb = ((t + 1) & 1) * 1024;             // previous enc_hx buffer
      for (int i = tid; i < 1024; i += NTHR)
        S.xs[128 + i] = ldgc(ws + HENC_OFF + hb + i);
    }
    __syncthreads();
    {
      float a = hw_dot<F32>(p.eWih, grow * 128, S.xs, 128, lane)
              + hw_dot<F32>(p.eWhh, grow * 1024, S.xs + 128, 1024, lane)
              + S.bias_e[hw];
      if (lane == 0) S.g16[hw] = a;
    }
    __syncthreads();
    if (tid < 4){
      float gi = sigm(S.g16[tid]), gf = sigm(S.g16[4 + tid]),
            gg = tanhx(S.g16[8 + tid]), go = sigm(S.g16[12 + tid]);
      float c = gf * S.encc[tid] + gi * gg;
      float h = go * tanhx(c);
      S.encc[tid] = c;
      stg(ws + HENC_OFF + (t & 1) * 1024 + 4 * w + tid, h);
      stg(ws + CENC_OFF + 4 * w + tid, c);
    }
    target += NWG; gbar(cnt, target, &S.bail);

    // ============ R2: heads dhx/dcx + enc_score ============
    for (int i = tid; i < 1024; i += NTHR){
      S.xs[i]        = ldgc(ws + HENC_OFF + (t & 1) * 1024 + i);
      S.xs[1024 + i] = ldgc(ws + CENC_OFF + i);
    }
    if (w == 4 && tid < 64){        // re-zero sv/fv bufs 0,1 (consumed last step)
      stg(ws + SV_OFF + tid, 0.f);       stg(ws + FV_OFF + tid, 0.f);
      stg(ws + SV_OFF + 64 + tid, 0.f);  stg(ws + FV_OFF + 64 + tid, 0.f);
    }
    __syncthreads();
    if (hw < 4){
      float d = fmaxf(hw_dot<F32>(p.hxW, (long)(4 * w + hw) * 1024, S.xs, 1024, lane)
                      + S.hxb4[hw], 0.f);
      if (lane == 0) stg(ws + DH_OFF + 4 * w + hw, d);
    } else if (hw < 8){
      int j = hw - 4;
      float d = fmaxf(hw_dot<F32>(p.cxW, (long)(4 * w + j) * 1024, S.xs + 1024, 1024, lane)
                      + S.cxb4[j], 0.f);
      if (lane == 0) S.dcx_s[j] = d;   // decoder c, reused by all 3 iters (ref bug)
    } else if (w == 8){              // designated WG: enc_score output
      for (int rr = 0; rr < 8; ++rr){
        int r = (hw - 8) * 8 + rr;
        float s = hw_dot<F32>(p.clsW, (long)r * 1024, S.xs, 1024, lane) + S.clsb[r];
        if (lane == 0) stO<F32>(p.out, t * 64 + r, s);
      }
    }
    target += NWG; gbar(cnt, target, &S.bail);

    // ============ R3: decoder iter 1 (fusion_in = 0) ============
    for (int i = tid; i < 1024; i += NTHR)
      S.xs[i] = ldgc(ws + DH_OFF + i);
    if (w == 5 && tid < 64){         // re-zero sv/fv buf 2 (consumed in R1)
      stg(ws + SV_OFF + 128 + tid, 0.f);  stg(ws + FV_OFF + 128 + tid, 0.f);
    }
    __syncthreads();
    {
      float a = hw_dot<F32>(p.dWhh, grow * 1024, S.xs, 1024, lane) + S.bias_d[hw];
      if (lane == 0) S.g16[hw] = a;
    }
    __syncthreads();
    if (tid < 4){
      float gi = sigm(S.g16[tid]), gf = sigm(S.g16[4 + tid]),
            gg = tanhx(S.g16[8 + tid]), go = sigm(S.g16[12 + tid]);
      float c = gf * S.dcx_s[tid] + gi * gg;
      float h = go * tanhx(c);
      S.h4[tid] = h;
      stg(ws + DD_OFF + 4 * w + tid, h);
    }
    __syncthreads();
    if (tid < 64){                    // split-K partials for cls@dhx1, futW@dhx1
      float sv = 0.f, fv = 0.f;
      #pragma unroll
      for (int j = 0; j < 4; ++j){
        sv = fmaf(S.cls_sl[tid * 4 + j], S.h4[j], sv);
        fv = fmaf(S.fut_sl[tid * 4 + j], S.h4[j], fv);
      }
      unsafeAtomicAdd(ws + SV_OFF + tid, sv);
      unsafeAtomicAdd(ws + FV_OFF + tid, fv);
    }
    target += NWG; gbar(cnt, target, &S.bail);

    // ============ R4/R5: decoder iters 2,3 ============
    for (int di = 1; di <= 2; ++di){
      const int bin = di - 1, bout = di;
      float* ddin  = ws + DD_OFF + ((di - 1) & 1) * 1024;
      float* ddout = ws + DD_OFF + (di & 1) * 1024;
      if (tid < 64){
        float s = ldgc(ws + SV_OFF + bin * 64 + tid) + S.clsb[tid];
        S.dsbuf[tid] = s;
        if ((di == 1 && w == 16) || (di == 2 && w == 24))
          stO<F32>(p.out, TSTEPS * 64 + (t * 3 + (di - 1)) * 64 + tid, s);
        float f = fmaxf(ldgc(ws + FV_OFF + bin * 64 + tid) + S.futb[tid], 0.f);
        S.fut_acc[tid] += f;
      }
      for (int i = tid; i < 1024; i += NTHR)
        S.xs[1024 + i] = ldgc(ddin + i);
      __syncthreads();
      {   // fusion_in = relu(fus_W @ ds + fus_b), redundant per WG from LDS FT
        int h0 = tid * 2;
        float a0 = S.fusb[h0], a1 = S.fusb[h0 + 1];
        for (int o = 0; o < 64; ++o){
          u32t pr = *(const u32t*)&S.FT[o * 1024 + h0];
          float d = S.dsbuf[o];
          a0 = fmaf(bfu((u16t)(pr & 0xffff)), d, a0);
          a1 = fmaf(bfu((u16t)(pr >> 16)), d, a1);
        }
        S.xs[h0]     = fmaxf(a0, 0.f);
        S.xs[h0 + 1] = fmaxf(a1, 0.f);
      }
      __syncthreads();
      {
        float a = hw_dot<F32>(p.dWih, grow * 1024, S.xs, 1024, lane)
                + hw_dot<F32>(p.dWhh, grow * 1024, S.xs + 1024, 1024, lane)
                + S.bias_d[hw];
        if (lane == 0) S.g16[hw] = a;
      }
      __syncthreads();
      if (tid < 4){
        float gi = sigm(S.g16[tid]), gf = sigm(S.g16[4 + tid]),
              gg = tanhx(S.g16[8 + tid]), go = sigm(S.g16[12 + tid]);
        float c = gf * S.dcx_s[tid] + gi * gg;
        float h = go * tanhx(c);
        S.h4[tid] = h;
        if (di == 1) stg(ddout + 4 * w + tid, h);   // dhx3 never re-read as vector
      }
      __syncthreads();
      if (tid < 64){
        float sv = 0.f, fv = 0.f;
        #pragma unroll
        for (int j = 0; j < 4; ++j){
          sv = fmaf(S.cls_sl[tid * 4 + j], S.h4[j], sv);
          fv = fmaf(S.fut_sl[tid * 4 + j], S.h4[j], fv);
        }
        unsafeAtomicAdd(ws + SV_OFF + bout * 64 + tid, sv);
        unsafeAtomicAdd(ws + FV_OFF + bout * 64 + tid, fv);
      }
      target += NWG; gbar(cnt, target, &S.bail);
    }
  }

  // epilogue: ds3 of the final step
  if (w == 32 && tid < 64){
    float s = ldgc(ws + SV_OFF + 128 + tid) + S.clsb[tid];
    stO<F32>(p.out, TSTEPS * 64 + ((TSTEPS - 1) * 3 + 2) * 64 + tid, s);
  }
}

__global__ __launch_bounds__(NTHR, 1)
void trn_persist(Params p){
  __shared__ SharedMem S;
  // ---- runtime input-dtype detection from X's bit patterns ----
  // bf16 N(0,1) data: every u16 has exponent field in ~[110,130].
  // f32 data: low-mantissa u16 halves are ~uniform random -> exponent 0 or
  // >=141 with p~0.45 each; >=3 hits in 256 words => f32 (certain).
  if (threadIdx.x == 0){ S.bail = 0; S.badcnt = 0; }
  __syncthreads();
  if (threadIdx.x < 256){
    u16t u = ((const u16t*)p.X)[threadIdx.x];
    int e = (u >> 7) & 0xff;
    if (e == 0 || e >= 141) atomicAdd(&S.badcnt, 1);
  }
  __syncthreads();
  if (S.badcnt >= 3) run<true>(p, S);
  else               run<false>(p, S);
}

__global__ void ws_init(float* ws){
  int i = blockIdx.x * blockDim.x + threadIdx.x;
  if (i < WS_ZERO_N) ws[i] = 0.f;
}

extern "C" void kernel_launch(void* const* d_in, const int* in_sizes, int n_in,
                              void* d_out, int out_size, void* d_ws, size_t ws_size,
                              hipStream_t stream){
  Params P;
  P.X      = d_in[0];
  P.eWih   = d_in[1];
  P.eWhh   = d_in[2];
  P.ebih   = d_in[3];
  P.ebhh   = d_in[4];
  P.dWih   = d_in[5];
  P.dWhh   = d_in[6];
  P.dbih   = d_in[7];
  P.dbhh   = d_in[8];
  P.hxW    = d_in[9];
  P.hxb    = d_in[10];
  P.cxW    = d_in[11];
  P.cxb    = d_in[12];
  P.fusW   = d_in[13];
  P.fusb_g = d_in[14];
  P.futW   = d_in[15];
  P.futb_g = d_in[16];
  P.clsW   = d_in[17];
  P.clsb_g = d_in[18];
  P.ws     = (float*)d_ws;
  P.out    = d_out;

  ws_init<<<(WS_ZERO_N + 255) / 256, 256, 0, stream>>>(P.ws);

  void* args[] = { &P };
  hipLaunchCooperativeKernel((void*)trn_persist, dim3(NWG), dim3(NTHR),
                             args, 0, stream);
}

// Round 3
// 88541.779 us; speedup vs baseline: 1.5640x; 1.5640x over previous
//
#include <hip/hip_runtime.h>
#include <hip/hip_bf16.h>

// Persistent cooperative RNN kernel for MI355X (gfx950).
// 256 WGs x 512 threads, 1 WG/CU (~147KB LDS). Each WG owns 4 hidden rows =>
// 16 gate rows of every 4H weight matrix. 5 grid barriers per time step via a
// two-level (8x32) tree barrier on LIC-resident counters.
// Encoder weights live in LDS as f32 (recurrent path precision), decoder
// weights in LDS as bf16, fus_W rows in per-thread VGPRs. Heads/cls stream
// from per-XCD L2. Cross-WG activations move via relaxed agent-scope atomics
// (coherence-point direct) so no cache-invalidating fences are needed.
// Input/output dtype (f32 vs bf16) is detected at runtime from X's bit
// patterns and the whole body is templated on it.

typedef unsigned short u16t;
typedef unsigned int u32t;

#define TSTEPS 2045
#define NWG 256
#define NTHR 512

// d_ws float offsets
#define CNT_OFF   0      // root barrier counter (u32)
#define GRP_OFF   64     // 8 group counters, stride 64 floats (256B)
#define HENC_OFF  640    // enc h, ping-pong [2][1024]
#define CENC_OFF  2688   // enc c gather [1024]
#define DH_OFF    3712   // head dhx [1024]
#define DD_OFF    4736   // dec h ping-pong [2][1024]
#define SV_OFF    6784   // split-K cls partials [3][64]
#define FV_OFF    6976   // split-K fut partials [3][64]
#define WS_ZERO_N 8192

struct Params {
  const void *X, *eWih, *eWhh, *ebih, *ebhh, *dWih, *dWhh, *dbih, *dbhh,
             *hxW, *hxb, *cxW, *cxb, *fusW, *fusb_g, *futW, *futb_g, *clsW, *clsb_g;
  float* ws;
  void* out;
};

struct SharedMem {
  alignas(16) float encW[16 * 1152];   // [row][Wih(128)|Whh(1024)] f32, 73728B
  alignas(16) u16t  decW[16 * 2048];   // [row][Wih(1024)|Whh(1024)] bf16, 65536B
  alignas(16) float xs[2048];          // staged input vector(s) for dots
  float cls_sl[256], fut_sl[256];      // [o][j]: this WG's 4 columns
  float clsb[64], futb[64], fut_acc[64], dsbuf[64];
  float bias_e[16], bias_d[16], g16[16];
  float h4[4], dcx_s[4], encc[4], hxb4[4], cxb4[4];
  int bail;
  int badcnt;
};

__device__ __forceinline__ float bfu(u16t u){
  union { u32t i; float f; } v; v.i = ((u32t)u) << 16; return v.f;
}
__device__ __forceinline__ u16t bf16bits(float v){
  __hip_bfloat16 b = __float2bfloat16(v);
  union { __hip_bfloat16 b; u16t u; } c; c.b = b; return c.u;
}
template<bool F32>
__device__ __forceinline__ float ldE(const void* p, int i){
  if (F32) return ((const float*)p)[i];
  return bfu(((const u16t*)p)[i]);
}
template<bool F32>
__device__ __forceinline__ u16t ldB(const void* p, int i){   // load as bf16 bits
  if (F32) return bf16bits(((const float*)p)[i]);
  return ((const u16t*)p)[i];
}
template<bool F32>
__device__ __forceinline__ void stO(void* p, int i, float v){
  if (F32) ((float*)p)[i] = v;
  else     ((u16t*)p)[i] = bf16bits(v);
}
__device__ __forceinline__ float sigm(float x){ return 1.f / (1.f + __expf(-x)); }
__device__ __forceinline__ float tanhx(float x){
  float e = __expf(-2.f * fabsf(x));
  float t = (1.f - e) / (1.f + e);
  return copysignf(t, x);
}
// Coherence-point (agent scope, relaxed) store/load: visible across XCDs
// without fences.
__device__ __forceinline__ void stg(float* p, float v){
  __hip_atomic_store(p, v, __ATOMIC_RELAXED, __HIP_MEMORY_SCOPE_AGENT);
}
__device__ __forceinline__ float ldgc(const float* p){
  return __hip_atomic_load(p, __ATOMIC_RELAXED, __HIP_MEMORY_SCOPE_AGENT);
}

// Half-wave (32 lanes) dot of weight row (GLOBAL, f32 or bf16) with f32 x (LDS).
template<bool F32>
__device__ __forceinline__ float hw_dot(const void* wbase, long off,
                                        const float* __restrict__ x,
                                        int K, int lane){
  float acc = 0.f;
  if (F32){
    const float* w = (const float*)wbase + off;
    for (int c = lane * 4; c < K; c += 128){
      float4 wv = *(const float4*)(w + c);
      float4 xv = *(const float4*)(x + c);
      acc = fmaf(wv.x, xv.x, acc); acc = fmaf(wv.y, xv.y, acc);
      acc = fmaf(wv.z, xv.z, acc); acc = fmaf(wv.w, xv.w, acc);
    }
  } else {
    const u16t* w = (const u16t*)wbase + off;
    for (int c = lane * 4; c < K; c += 128){
      ushort4 wv = *(const ushort4*)(w + c);
      float4  xv = *(const float4*)(x + c);
      acc = fmaf(bfu(wv.x), xv.x, acc); acc = fmaf(bfu(wv.y), xv.y, acc);
      acc = fmaf(bfu(wv.z), xv.z, acc); acc = fmaf(bfu(wv.w), xv.w, acc);
    }
  }
  #pragma unroll
  for (int o = 16; o; o >>= 1) acc += __shfl_xor(acc, o, 64);
  return acc;
}

// Half-wave dot of f32 LDS weight row with f32 LDS x.
__device__ __forceinline__ float lds_dot_f32(const float* __restrict__ w,
                                             const float* __restrict__ x,
                                             int K, int lane){
  float acc = 0.f;
  for (int c = lane * 4; c < K; c += 128){
    float4 wv = *(const float4*)(w + c);
    float4 xv = *(const float4*)(x + c);
    acc = fmaf(wv.x, xv.x, acc); acc = fmaf(wv.y, xv.y, acc);
    acc = fmaf(wv.z, xv.z, acc); acc = fmaf(wv.w, xv.w, acc);
  }
  #pragma unroll
  for (int o = 16; o; o >>= 1) acc += __shfl_xor(acc, o, 64);
  return acc;
}

// Half-wave dot of bf16 LDS weight row with f32 LDS x.
__device__ __forceinline__ float lds_dot_bf16(const u16t* __restrict__ w,
                                              const float* __restrict__ x,
                                              int K, int lane){
  float acc = 0.f;
  for (int c = lane * 8; c < K; c += 256){
    uint4  wv = *(const uint4*)(w + c);
    float4 x0 = *(const float4*)(x + c);
    float4 x1 = *(const float4*)(x + c + 4);
    acc = fmaf(bfu((u16t)(wv.x & 0xffff)), x0.x, acc);
    acc = fmaf(bfu((u16t)(wv.x >> 16)),    x0.y, acc);
    acc = fmaf(bfu((u16t)(wv.y & 0xffff)), x0.z, acc);
    acc = fmaf(bfu((u16t)(wv.y >> 16)),    x0.w, acc);
    acc = fmaf(bfu((u16t)(wv.z & 0xffff)), x1.x, acc);
    acc = fmaf(bfu((u16t)(wv.z >> 16)),    x1.y, acc);
    acc = fmaf(bfu((u16t)(wv.w & 0xffff)), x1.z, acc);
    acc = fmaf(bfu((u16t)(wv.w >> 16)),    x1.w, acc);
  }
  #pragma unroll
  for (int o = 16; o; o >>= 1) acc += __shfl_xor(acc, o, 64);
  return acc;
}

// Two-level tree barrier: 8 group counters (32 arrivals each, on separate
// 256B-spaced lines) -> root (8 arrivals). All waves spin on root.
// vmcnt(0) drains this wave's stores/atomics before arrival.
// Anti-hang: ~35ms timeout then finish wrong (never hang the harness).
__device__ __forceinline__ void gbar(float* ws, u32t epoch, int grp, int* bail){
  asm volatile("s_waitcnt vmcnt(0)" ::: "memory");
  __syncthreads();
  if (threadIdx.x == 0 && !(*bail)){
    u32t* g = (u32t*)(ws + GRP_OFF + grp * 64);
    u32t* r = (u32t*)(ws + CNT_OFF);
    u32t old = __hip_atomic_fetch_add(g, 1u, __ATOMIC_RELAXED, __HIP_MEMORY_SCOPE_AGENT);
    if (old + 1 == epoch * 32)
      __hip_atomic_fetch_add(r, 1u, __ATOMIC_RELAXED, __HIP_MEMORY_SCOPE_AGENT);
    int spins = 0;
    while (__hip_atomic_load(r, __ATOMIC_RELAXED, __HIP_MEMORY_SCOPE_AGENT) < epoch * 8){
      __builtin_amdgcn_s_sleep(2);
      if (++spins > (1 << 16)) { *bail = 1; break; }
    }
  }
  __syncthreads();
}

template<bool F32>
__device__ void run(const Params& p, SharedMem& S){
  const int tid  = threadIdx.x;
  const int w    = blockIdx.x;
  const int grp  = w >> 5;
  const int hw   = tid >> 5;            // half-wave 0..15 -> one gate row each
  const int lane = tid & 31;
  const long grow = (long)((hw >> 2) * 1024 + 4 * w + (hw & 3));  // gate row
  float* ws = p.ws;

  // ---------- startup: stage per-WG weights into LDS ----------
  {   // each half-wave stages its own enc (f32) and dec (bf16) rows
    float* er = S.encW + hw * 1152;
    for (int c = lane; c < 128; c += 32)  er[c]       = ldE<F32>(p.eWih, (int)(grow * 128 + c));
    for (int c = lane; c < 1024; c += 32) er[128 + c] = ldE<F32>(p.eWhh, (int)(grow * 1024 + c));
    u16t* dr = S.decW + hw * 2048;
    for (int c = lane; c < 1024; c += 32){
      dr[c]        = ldB<F32>(p.dWih, (int)(grow * 1024 + c));
      dr[1024 + c] = ldB<F32>(p.dWhh, (int)(grow * 1024 + c));
    }
  }
  // fus_W rows for this thread's two h outputs -> registers
  u32t fw[64];
  float fusb0, fusb1;
  {
    int h0 = 2 * tid, h1 = 2 * tid + 1;
    #pragma unroll
    for (int o = 0; o < 64; ++o){
      u16t lo = ldB<F32>(p.fusW, h0 * 64 + o);
      u16t hi = ldB<F32>(p.fusW, h1 * 64 + o);
      fw[o] = ((u32t)hi << 16) | lo;
    }
    fusb0 = ldE<F32>(p.fusb_g, h0);
    fusb1 = ldE<F32>(p.fusb_g, h1);
  }
  if (tid < 256){
    int o = tid >> 2, j = tid & 3;
    S.cls_sl[tid] = ldE<F32>(p.clsW, o * 1024 + 4 * w + j);
    S.fut_sl[tid] = ldE<F32>(p.futW, o * 1024 + 4 * w + j);
  }
  if (tid < 64){
    S.clsb[tid] = ldE<F32>(p.clsb_g, tid);
    S.futb[tid] = ldE<F32>(p.futb_g, tid);
    S.fut_acc[tid] = 0.f;
  }
  if (tid < 16){
    int gr = (tid >> 2) * 1024 + 4 * w + (tid & 3);
    S.bias_e[tid] = ldE<F32>(p.ebih, gr) + ldE<F32>(p.ebhh, gr);
    S.bias_d[tid] = ldE<F32>(p.dbih, gr) + ldE<F32>(p.dbhh, gr);
  }
  if (tid < 4){
    S.hxb4[tid] = ldE<F32>(p.hxb, 4 * w + tid);
    S.cxb4[tid] = ldE<F32>(p.cxb, 4 * w + tid);
    S.encc[tid] = 0.f;
  }
  __syncthreads();

  u32t ep = 0;

  for (int t = 0; t < TSTEPS; ++t){
    // ============ R1: encoder gates ============
    if (tid < 64){
      S.xs[tid] = ldE<F32>(p.X, t * 64 + tid);         // fusion[0:64] = x_t
      float fv = 0.f;
      if (t > 0){
        float f3 = fmaxf(ldgc(ws + FV_OFF + 128 + tid) + S.futb[tid], 0.f);
        fv = (S.fut_acc[tid] + f3) * (1.f / 3.f);      // fut = mean of 3 relus
      }
      S.xs[64 + tid] = fv;                             // fusion[64:128] = fut
      S.fut_acc[tid] = 0.f;
      if (w == 32 && t > 0){                           // ds3 of previous step
        float s = ldgc(ws + SV_OFF + 128 + tid) + S.clsb[tid];
        stO<F32>(p.out, TSTEPS * 64 + ((t - 1) * 3 + 2) * 64 + tid, s);
      }
    }
    {
      const int hb = ((t + 1) & 1) * 1024;             // previous enc_hx buffer
      for (int i = tid; i < 1024; i += NTHR)
        S.xs[128 + i] = ldgc(ws + HENC_OFF + hb + i);
    }
    __syncthreads();
    {
      float a = lds_dot_f32(S.encW + hw * 1152, S.xs, 1152, lane) + S.bias_e[hw];
      if (lane == 0) S.g16[hw] = a;
    }
    __syncthreads();
    if (tid < 4){
      float gi = sigm(S.g16[tid]), gf = sigm(S.g16[4 + tid]),
            gg = tanhx(S.g16[8 + tid]), go = sigm(S.g16[12 + tid]);
      float c = gf * S.encc[tid] + gi * gg;
      float h = go * tanhx(c);
      S.encc[tid] = c;
      stg(ws + HENC_OFF + (t & 1) * 1024 + 4 * w + tid, h);
      stg(ws + CENC_OFF + 4 * w + tid, c);
    }
    ++ep; gbar(ws, ep, grp, &S.bail);

    // ============ R2: heads dhx/dcx + enc_score ============
    for (int i = tid; i < 1024; i += NTHR){
      S.xs[i]        = ldgc(ws + HENC_OFF + (t & 1) * 1024 + i);
      S.xs[1024 + i] = ldgc(ws + CENC_OFF + i);
    }
    if (w == 4 && tid < 64){        // re-zero sv/fv bufs 0,1 (consumed last step)
      stg(ws + SV_OFF + tid, 0.f);       stg(ws + FV_OFF + tid, 0.f);
      stg(ws + SV_OFF + 64 + tid, 0.f);  stg(ws + FV_OFF + 64 + tid, 0.f);
    }
    __syncthreads();
    if (hw < 4){
      float d = fmaxf(hw_dot<F32>(p.hxW, (long)(4 * w + hw) * 1024, S.xs, 1024, lane)
                      + S.hxb4[hw], 0.f);
      if (lane == 0) stg(ws + DH_OFF + 4 * w + hw, d);
    } else if (hw < 8){
      int j = hw - 4;
      float d = fmaxf(hw_dot<F32>(p.cxW, (long)(4 * w + j) * 1024, S.xs + 1024, 1024, lane)
                      + S.cxb4[j], 0.f);
      if (lane == 0) S.dcx_s[j] = d;   // decoder c, reused by all 3 iters (ref bug)
    } else if (w >= 8 && w < 16){      // 8 WGs x 8 half-waves: enc_score, 1 dot each
      int r = (w - 8) * 8 + (hw - 8);
      float s = hw_dot<F32>(p.clsW, (long)r * 1024, S.xs, 1024, lane) + S.clsb[r];
      if (lane == 0) stO<F32>(p.out, t * 64 + r, s);
    }
    ++ep; gbar(ws, ep, grp, &S.bail);

    // ============ R3: decoder iter 1 (fusion_in = 0) ============
    for (int i = tid; i < 1024; i += NTHR)
      S.xs[i] = ldgc(ws + DH_OFF + i);
    if (w == 5 && tid < 64){         // re-zero sv/fv buf 2 (consumed in R1)
      stg(ws + SV_OFF + 128 + tid, 0.f);  stg(ws + FV_OFF + 128 + tid, 0.f);
    }
    __syncthreads();
    {
      float a = lds_dot_bf16(S.decW + hw * 2048 + 1024, S.xs, 1024, lane) + S.bias_d[hw];
      if (lane == 0) S.g16[hw] = a;
    }
    __syncthreads();
    if (tid < 4){
      float gi = sigm(S.g16[tid]), gf = sigm(S.g16[4 + tid]),
            gg = tanhx(S.g16[8 + tid]), go = sigm(S.g16[12 + tid]);
      float c = gf * S.dcx_s[tid] + gi * gg;
      float h = go * tanhx(c);
      S.h4[tid] = h;
      stg(ws + DD_OFF + 4 * w + tid, h);
    }
    __syncthreads();
    if (tid < 64){                    // split-K partials for cls@dhx1, futW@dhx1
      float sv = 0.f, fv = 0.f;
      #pragma unroll
      for (int j = 0; j < 4; ++j){
        sv = fmaf(S.cls_sl[tid * 4 + j], S.h4[j], sv);
        fv = fmaf(S.fut_sl[tid * 4 + j], S.h4[j], fv);
      }
      unsafeAtomicAdd(ws + SV_OFF + tid, sv);
      unsafeAtomicAdd(ws + FV_OFF + tid, fv);
    }
    ++ep; gbar(ws, ep, grp, &S.bail);

    // ============ R4/R5: decoder iters 2,3 ============
    for (int di = 1; di <= 2; ++di){
      const int bin = di - 1, bout = di;
      float* ddin  = ws + DD_OFF + ((di - 1) & 1) * 1024;
      float* ddout = ws + DD_OFF + (di & 1) * 1024;
      if (tid < 64){
        float s = ldgc(ws + SV_OFF + bin * 64 + tid) + S.clsb[tid];
        S.dsbuf[tid] = s;
        if ((di == 1 && w == 16) || (di == 2 && w == 24))
          stO<F32>(p.out, TSTEPS * 64 + (t * 3 + (di - 1)) * 64 + tid, s);
        float f = fmaxf(ldgc(ws + FV_OFF + bin * 64 + tid) + S.futb[tid], 0.f);
        S.fut_acc[tid] += f;
      }
      for (int i = tid; i < 1024; i += NTHR)
        S.xs[1024 + i] = ldgc(ddin + i);
      __syncthreads();
      {   // fusion_in = relu(fus_W @ ds + fus_b), per-thread 2 rows from VGPRs
        float a0 = fusb0, a1 = fusb1;
        #pragma unroll
        for (int o = 0; o < 64; ++o){
          float d = S.dsbuf[o];
          a0 = fmaf(bfu((u16t)(fw[o] & 0xffff)), d, a0);
          a1 = fmaf(bfu((u16t)(fw[o] >> 16)),    d, a1);
        }
        S.xs[2 * tid]     = fmaxf(a0, 0.f);
        S.xs[2 * tid + 1] = fmaxf(a1, 0.f);
      }
      __syncthreads();
      {
        float a = lds_dot_bf16(S.decW + hw * 2048, S.xs, 2048, lane) + S.bias_d[hw];
        if (lane == 0) S.g16[hw] = a;
      }
      __syncthreads();
      if (tid < 4){
        float gi = sigm(S.g16[tid]), gf = sigm(S.g16[4 + tid]),
              gg = tanhx(S.g16[8 + tid]), go = sigm(S.g16[12 + tid]);
        float c = gf * S.dcx_s[tid] + gi * gg;
        float h = go * tanhx(c);
        S.h4[tid] = h;
        if (di == 1) stg(ddout + 4 * w + tid, h);   // dhx3 never re-read as vector
      }
      __syncthreads();
      if (tid < 64){
        float sv = 0.f, fv = 0.f;
        #pragma unroll
        for (int j = 0; j < 4; ++j){
          sv = fmaf(S.cls_sl[tid * 4 + j], S.h4[j], sv);
          fv = fmaf(S.fut_sl[tid * 4 + j], S.h4[j], fv);
        }
        unsafeAtomicAdd(ws + SV_OFF + bout * 64 + tid, sv);
        unsafeAtomicAdd(ws + FV_OFF + bout * 64 + tid, fv);
      }
      ++ep; gbar(ws, ep, grp, &S.bail);
    }
  }

  // epilogue: ds3 of the final step
  if (w == 32 && tid < 64){
    float s = ldgc(ws + SV_OFF + 128 + tid) + S.clsb[tid];
    stO<F32>(p.out, TSTEPS * 64 + ((TSTEPS - 1) * 3 + 2) * 64 + tid, s);
  }
}

__global__ __launch_bounds__(NTHR, 2)
void trn_persist(Params p){
  __shared__ SharedMem S;
  // ---- runtime input-dtype detection from X's bit patterns ----
  // bf16 N(0,1) data: every u16 has exponent field in ~[110,130].
  // f32 data: low-mantissa u16 halves are ~uniform random -> exponent 0 or
  // >=141 with p~0.45 each; >=3 hits in 256 words => f32 (certain).
  if (threadIdx.x == 0){ S.bail = 0; S.badcnt = 0; }
  __syncthreads();
  if (threadIdx.x < 256){
    u16t u = ((const u16t*)p.X)[threadIdx.x];
    int e = (u >> 7) & 0xff;
    if (e == 0 || e >= 141) atomicAdd(&S.badcnt, 1);
  }
  __syncthreads();
  if (S.badcnt >= 3) run<true>(p, S);
  else               run<false>(p, S);
}

__global__ void ws_init(float* ws){
  int i = blockIdx.x * blockDim.x + threadIdx.x;
  if (i < WS_ZERO_N) ws[i] = 0.f;
}

extern "C" void kernel_launch(void* const* d_in, const int* in_sizes, int n_in,
                              void* d_out, int out_size, void* d_ws, size_t ws_size,
                              hipStream_t stream){
  Params P;
  P.X      = d_in[0];
  P.eWih   = d_in[1];
  P.eWhh   = d_in[2];
  P.ebih   = d_in[3];
  P.ebhh   = d_in[4];
  P.dWih   = d_in[5];
  P.dWhh   = d_in[6];
  P.dbih   = d_in[7];
  P.dbhh   = d_in[8];
  P.hxW    = d_in[9];
  P.hxb    = d_in[10];
  P.cxW    = d_in[11];
  P.cxb    = d_in[12];
  P.fusW   = d_in[13];
  P.fusb_g = d_in[14];
  P.futW   = d_in[15];
  P.futb_g = d_in[16];
  P.clsW   = d_in[17];
  P.clsb_g = d_in[18];
  P.ws     = (float*)d_ws;
  P.out    = d_out;

  ws_init<<<(WS_ZERO_N + 255) / 256, 256, 0, stream>>>(P.ws);

  void* args[] = { &P };
  hipLaunchCooperativeKernel((void*)trn_persist, dim3(NWG), dim3(NTHR),
                             args, 0, stream);
}

// Round 5
// 82940.424 us; speedup vs baseline: 1.6696x; 1.0675x over previous
//
#include <hip/hip_runtime.h>
#include <hip/hip_bf16.h>

// Persistent cooperative RNN kernel for MI355X (gfx950).
// 256 WGs x 512 threads, 1 WG/CU (~151KB LDS). Each WG owns 4 hidden rows =>
// 16 gate rows of every 4H weight matrix. 5 grid barriers per time step via a
// two-level (8x32) tree barrier with per-group release lines.
// Enc weights f32 in LDS, dec weights bf16 in LDS, fus_W rows in VGPRs.
// Cross-WG vectors move via coherent loads (sc0 sc1 dwordx4) and agent-scope
// atomic stores; split-K cls/fut products go through a double-buffered
// transposed partial array reduced redundantly per WG (no atomic storms).

typedef unsigned short u16t;
typedef unsigned int u32t;

#define TSTEPS 2045
#define NWG 256
#define NTHR 512

// d_ws float offsets
#define CNT_OFF   0      // root barrier counter (u32)
#define GRP_OFF   64     // 8 group arrival counters, stride 64 floats (256B)
#define REL_OFF   576    // 8 group release epochs, stride 64 floats
#define HENC_OFF  1088   // enc h, ping-pong [2][1024]
#define CENC_OFF  3136   // enc c gather [1024]
#define DH_OFF    4160   // head dhx [1024]
#define DD_OFF    5184   // dec h ping-pong [2][1024]
#define PART_OFF  7424   // split-K partials, [2][128 outputs][256 wg] floats
#define WS_ZERO_N 5184

struct Params {
  const void *X, *eWih, *eWhh, *ebih, *ebhh, *dWih, *dWhh, *dbih, *dbhh,
             *hxW, *hxb, *cxW, *cxb, *fusW, *fusb_g, *futW, *futb_g, *clsW, *clsb_g;
  float* ws;
  void* out;
};

struct SharedMem {
  alignas(16) float encW[16 * 1152];   // [row][Wih(128)|Whh(1024)] f32, 73728B
  alignas(16) u16t  decW[16 * 2048];   // [row][Wih(1024)|Whh(1024)] bf16, 65536B
  alignas(16) float xs[2048];          // staged input vector(s) for dots
  float cls_sl[256], fut_sl[256];      // [o][j]: this WG's 4 columns
  float clsb[64], futb[64], fut_acc[64], dsbuf[64], fv3[64];
  float bias_e[16], bias_d[16], g16[16];
  float h4[4], c4[4], dcx_s[4], encc[4], hxb4[4], cxb4[4];
  int bail;
  int badcnt;
};

__device__ __forceinline__ float bfu(u16t u){
  union { u32t i; float f; } v; v.i = ((u32t)u) << 16; return v.f;
}
__device__ __forceinline__ u16t bf16bits(float v){
  __hip_bfloat16 b = __float2bfloat16(v);
  union { __hip_bfloat16 b; u16t u; } c; c.b = b; return c.u;
}
template<bool F32>
__device__ __forceinline__ float ldE(const void* p, int i){
  if (F32) return ((const float*)p)[i];
  return bfu(((const u16t*)p)[i]);
}
template<bool F32>
__device__ __forceinline__ u16t ldB(const void* p, int i){   // load as bf16 bits
  if (F32) return bf16bits(((const float*)p)[i]);
  return ((const u16t*)p)[i];
}
template<bool F32>
__device__ __forceinline__ void stO(void* p, int i, float v){
  if (F32) ((float*)p)[i] = v;
  else     ((u16t*)p)[i] = bf16bits(v);
}
__device__ __forceinline__ float sigm(float x){ return 1.f / (1.f + __expf(-x)); }
__device__ __forceinline__ float tanhx(float x){
  float e = __expf(-2.f * fabsf(x));
  float t = (1.f - e) / (1.f + e);
  return copysignf(t, x);
}
// Coherence-point scalar store/load (agent scope, relaxed).
__device__ __forceinline__ void stg(float* p, float v){
  __hip_atomic_store(p, v, __ATOMIC_RELAXED, __HIP_MEMORY_SCOPE_AGENT);
}
// 64-bit coherent store (two floats) via agent-scope atomic on bit-cast u64.
__device__ __forceinline__ void st2c(float* p, float a, float b){
  union { float f[2]; unsigned long long u; } c;
  c.f[0] = a; c.f[1] = b;
  __hip_atomic_store((unsigned long long*)p, c.u,
                     __ATOMIC_RELAXED, __HIP_MEMORY_SCOPE_AGENT);
}
__device__ __forceinline__ void st4c(float* p, const float* v4){
  st2c(p, v4[0], v4[1]);
  st2c(p + 2, v4[2], v4[3]);
}
// Coherent 16B load: sc0+sc1 bypasses L1 + per-XCD L2 (device coherence point).
__device__ __forceinline__ float4 ld4c(const float* p){
  float4 r;
  asm volatile("global_load_dwordx4 %0, %1, off sc0 sc1\n\t"
               "s_waitcnt vmcnt(0)"
               : "=&v"(r) : "v"(p) : "memory");
  return r;
}
// 8 coherent 16B loads with a single wait (batched latency).
__device__ __forceinline__ void ld4c8(const float* p0, const float* p1,
                                      const float* p2, const float* p3,
                                      const float* p4, const float* p5,
                                      const float* p6, const float* p7,
                                      float4& r0, float4& r1, float4& r2, float4& r3,
                                      float4& r4, float4& r5, float4& r6, float4& r7){
  asm volatile(
    "global_load_dwordx4 %0, %8, off sc0 sc1\n\t"
    "global_load_dwordx4 %1, %9, off sc0 sc1\n\t"
    "global_load_dwordx4 %2, %10, off sc0 sc1\n\t"
    "global_load_dwordx4 %3, %11, off sc0 sc1\n\t"
    "global_load_dwordx4 %4, %12, off sc0 sc1\n\t"
    "global_load_dwordx4 %5, %13, off sc0 sc1\n\t"
    "global_load_dwordx4 %6, %14, off sc0 sc1\n\t"
    "global_load_dwordx4 %7, %15, off sc0 sc1\n\t"
    "s_waitcnt vmcnt(0)"
    : "=&v"(r0), "=&v"(r1), "=&v"(r2), "=&v"(r3),
      "=&v"(r4), "=&v"(r5), "=&v"(r6), "=&v"(r7)
    : "v"(p0), "v"(p1), "v"(p2), "v"(p3), "v"(p4), "v"(p5), "v"(p6), "v"(p7)
    : "memory");
}

// Half-wave (32 lanes) dot of GLOBAL weight row with f32 x (LDS).
template<bool F32>
__device__ __forceinline__ float hw_dot(const void* wbase, long off,
                                        const float* __restrict__ x,
                                        int K, int lane){
  float acc = 0.f;
  if (F32){
    const float* w = (const float*)wbase + off;
    for (int c = lane * 4; c < K; c += 128){
      float4 wv = *(const float4*)(w + c);
      float4 xv = *(const float4*)(x + c);
      acc = fmaf(wv.x, xv.x, acc); acc = fmaf(wv.y, xv.y, acc);
      acc = fmaf(wv.z, xv.z, acc); acc = fmaf(wv.w, xv.w, acc);
    }
  } else {
    const u16t* w = (const u16t*)wbase + off;
    for (int c = lane * 4; c < K; c += 128){
      ushort4 wv = *(const ushort4*)(w + c);
      float4  xv = *(const float4*)(x + c);
      acc = fmaf(bfu(wv.x), xv.x, acc); acc = fmaf(bfu(wv.y), xv.y, acc);
      acc = fmaf(bfu(wv.z), xv.z, acc); acc = fmaf(bfu(wv.w), xv.w, acc);
    }
  }
  #pragma unroll
  for (int o = 16; o; o >>= 1) acc += __shfl_xor(acc, o, 64);
  return acc;
}

// Half-wave dot of f32 LDS weight row with f32 LDS x.
__device__ __forceinline__ float lds_dot_f32(const float* __restrict__ w,
                                             const float* __restrict__ x,
                                             int K, int lane){
  float acc = 0.f;
  for (int c = lane * 4; c < K; c += 128){
    float4 wv = *(const float4*)(w + c);
    float4 xv = *(const float4*)(x + c);
    acc = fmaf(wv.x, xv.x, acc); acc = fmaf(wv.y, xv.y, acc);
    acc = fmaf(wv.z, xv.z, acc); acc = fmaf(wv.w, xv.w, acc);
  }
  #pragma unroll
  for (int o = 16; o; o >>= 1) acc += __shfl_xor(acc, o, 64);
  return acc;
}

// Half-wave dot of bf16 LDS weight row with f32 LDS x.
__device__ __forceinline__ float lds_dot_bf16(const u16t* __restrict__ w,
                                              const float* __restrict__ x,
                                              int K, int lane){
  float acc = 0.f;
  for (int c = lane * 8; c < K; c += 256){
    uint4  wv = *(const uint4*)(w + c);
    float4 x0 = *(const float4*)(x + c);
    float4 x1 = *(const float4*)(x + c + 4);
    acc = fmaf(bfu((u16t)(wv.x & 0xffff)), x0.x, acc);
    acc = fmaf(bfu((u16t)(wv.x >> 16)),    x0.y, acc);
    acc = fmaf(bfu((u16t)(wv.y & 0xffff)), x0.z, acc);
    acc = fmaf(bfu((u16t)(wv.y >> 16)),    x0.w, acc);
    acc = fmaf(bfu((u16t)(wv.z & 0xffff)), x1.x, acc);
    acc = fmaf(bfu((u16t)(wv.z >> 16)),    x1.y, acc);
    acc = fmaf(bfu((u16t)(wv.w & 0xffff)), x1.z, acc);
    acc = fmaf(bfu((u16t)(wv.w >> 16)),    x1.w, acc);
  }
  #pragma unroll
  for (int o = 16; o; o >>= 1) acc += __shfl_xor(acc, o, 64);
  return acc;
}

// Tree barrier: 8 group arrival counters -> root; last root arriver writes 8
// per-group release lines; each WG polls only its group's line (32 pollers).
__device__ __forceinline__ void gbar(float* ws, u32t ep, int grp, int* bail){
  asm volatile("s_waitcnt vmcnt(0)" ::: "memory");
  __syncthreads();
  if (threadIdx.x == 0 && !(*bail)){
    u32t* g = (u32t*)(ws + GRP_OFF) + grp * 64;
    u32t old = __hip_atomic_fetch_add(g, 1u, __ATOMIC_RELAXED, __HIP_MEMORY_SCOPE_AGENT);
    if (old + 1u == ep * 32u){
      u32t* root = (u32t*)(ws + CNT_OFF);
      u32t ro = __hip_atomic_fetch_add(root, 1u, __ATOMIC_RELAXED, __HIP_MEMORY_SCOPE_AGENT);
      if (ro + 1u == ep * 8u){
        #pragma unroll
        for (int k = 0; k < 8; ++k)
          __hip_atomic_store((u32t*)(ws + REL_OFF) + k * 64, ep,
                             __ATOMIC_RELAXED, __HIP_MEMORY_SCOPE_AGENT);
      }
    }
    u32t* rel = (u32t*)(ws + REL_OFF) + grp * 64;
    int spins = 0;
    while (__hip_atomic_load(rel, __ATOMIC_RELAXED, __HIP_MEMORY_SCOPE_AGENT) < ep){
      __builtin_amdgcn_s_sleep(1);
      if (++spins > (1 << 15)) { *bail = 1; break; }
    }
  }
  __syncthreads();
}

// Reduce 256 partials for 8 outputs owned by this half-wave from PART[b].
// Outputs 0..63 -> dsbuf (+clsb); 64..127 -> fv3 = relu(sum+futb).
__device__ __forceinline__ void reduce_parts(const float* ws, int b, SharedMem& S,
                                             int hw, int lane){
  const float* q = ws + PART_OFF + b * 32768 + (hw * 8) * 256 + lane * 8;
  float4 A0,A1,A2,A3,A4,A5,A6,A7;
  float s[8];
  ld4c8(q, q + 4, q + 256, q + 260, q + 512, q + 516, q + 768, q + 772,
        A0,A1,A2,A3,A4,A5,A6,A7);
  s[0] = (A0.x+A0.y+A0.z+A0.w) + (A1.x+A1.y+A1.z+A1.w);
  s[1] = (A2.x+A2.y+A2.z+A2.w) + (A3.x+A3.y+A3.z+A3.w);
  s[2] = (A4.x+A4.y+A4.z+A4.w) + (A5.x+A5.y+A5.z+A5.w);
  s[3] = (A6.x+A6.y+A6.z+A6.w) + (A7.x+A7.y+A7.z+A7.w);
  ld4c8(q+1024, q+1028, q+1280, q+1284, q+1536, q+1540, q+1792, q+1796,
        A0,A1,A2,A3,A4,A5,A6,A7);
  s[4] = (A0.x+A0.y+A0.z+A0.w) + (A1.x+A1.y+A1.z+A1.w);
  s[5] = (A2.x+A2.y+A2.z+A2.w) + (A3.x+A3.y+A3.z+A3.w);
  s[6] = (A4.x+A4.y+A4.z+A4.w) + (A5.x+A5.y+A5.z+A5.w);
  s[7] = (A6.x+A6.y+A6.z+A6.w) + (A7.x+A7.y+A7.z+A7.w);
  #pragma unroll
  for (int r = 0; r < 8; ++r){
    float v = s[r];
    #pragma unroll
    for (int m = 16; m; m >>= 1) v += __shfl_xor(v, m, 64);
    if (lane == 0){
      int o = hw * 8 + r;
      if (o < 64) S.dsbuf[o] = v + S.clsb[o];
      else        S.fv3[o - 64] = fmaxf(v + S.futb[o - 64], 0.f);
    }
  }
}

template<bool F32>
__device__ void run(const Params& p, SharedMem& S){
  const int tid  = threadIdx.x;
  const int w    = blockIdx.x;
  const int grp  = w >> 5;
  const int hw   = tid >> 5;            // half-wave 0..15 -> one gate row each
  const int lane = tid & 31;
  const long grow = (long)((hw >> 2) * 1024 + 4 * w + (hw & 3));  // gate row
  float* ws = p.ws;

  // ---------- startup: stage per-WG weights into LDS ----------
  {
    float* er = S.encW + hw * 1152;
    for (int c = lane; c < 128; c += 32)  er[c]       = ldE<F32>(p.eWih, (int)(grow * 128 + c));
    for (int c = lane; c < 1024; c += 32) er[128 + c] = ldE<F32>(p.eWhh, (int)(grow * 1024 + c));
    u16t* dr = S.decW + hw * 2048;
    for (int c = lane; c < 1024; c += 32){
      dr[c]        = ldB<F32>(p.dWih, (int)(grow * 1024 + c));
      dr[1024 + c] = ldB<F32>(p.dWhh, (int)(grow * 1024 + c));
    }
  }
  // fus_W rows for this thread's two h outputs -> registers
  u32t fw[64];
  float fusb0, fusb1;
  {
    int h0 = 2 * tid, h1 = 2 * tid + 1;
    #pragma unroll
    for (int o = 0; o < 64; ++o){
      u16t lo = ldB<F32>(p.fusW, h0 * 64 + o);
      u16t hi = ldB<F32>(p.fusW, h1 * 64 + o);
      fw[o] = ((u32t)hi << 16) | lo;
    }
    fusb0 = ldE<F32>(p.fusb_g, h0);
    fusb1 = ldE<F32>(p.fusb_g, h1);
  }
  if (tid < 256){
    int o = tid >> 2, j = tid & 3;
    S.cls_sl[tid] = ldE<F32>(p.clsW, o * 1024 + 4 * w + j);
    S.fut_sl[tid] = ldE<F32>(p.futW, o * 1024 + 4 * w + j);
  }
  if (tid < 64){
    S.clsb[tid] = ldE<F32>(p.clsb_g, tid);
    S.futb[tid] = ldE<F32>(p.futb_g, tid);
    S.fut_acc[tid] = 0.f;
  }
  if (tid < 16){
    int gr = (tid >> 2) * 1024 + 4 * w + (tid & 3);
    S.bias_e[tid] = ldE<F32>(p.ebih, gr) + ldE<F32>(p.ebhh, gr);
    S.bias_d[tid] = ldE<F32>(p.dbih, gr) + ldE<F32>(p.dbhh, gr);
  }
  if (tid < 4){
    S.hxb4[tid] = ldE<F32>(p.hxb, 4 * w + tid);
    S.cxb4[tid] = ldE<F32>(p.cxb, 4 * w + tid);
    S.encc[tid] = 0.f;
  }
  __syncthreads();

  u32t ep = 0;

  for (int t = 0; t < TSTEPS; ++t){
    // ============ R1: encoder gates (+ ds3/fut3 from prev step's partials) ===
    if (tid < 256){
      const int hb = ((t + 1) & 1) * 1024;           // previous enc_hx buffer
      float4 v = ld4c(ws + HENC_OFF + hb + tid * 4);
      *(float4*)&S.xs[128 + tid * 4] = v;
    }
    if (t > 0) reduce_parts(ws, 1, S, hw, lane);     // dh3 partials -> dsbuf, fv3
    __syncthreads();
    if (tid < 64){
      S.xs[tid] = ldE<F32>(p.X, t * 64 + tid);       // fusion[0:64] = x_t
      float fv = 0.f;
      if (t > 0) fv = (S.fut_acc[tid] + S.fv3[tid]) * (1.f / 3.f);
      S.xs[64 + tid] = fv;                           // fusion[64:128] = fut
      S.fut_acc[tid] = 0.f;
      if (w == 32 && t > 0)                          // ds3 of previous step
        stO<F32>(p.out, TSTEPS * 64 + ((t - 1) * 3 + 2) * 64 + tid, S.dsbuf[tid]);
    }
    __syncthreads();
    {
      float a = lds_dot_f32(S.encW + hw * 1152, S.xs, 1152, lane) + S.bias_e[hw];
      if (lane == 0) S.g16[hw] = a;
    }
    __syncthreads();
    if (tid < 4){
      float gi = sigm(S.g16[tid]), gf = sigm(S.g16[4 + tid]),
            gg = tanhx(S.g16[8 + tid]), go = sigm(S.g16[12 + tid]);
      float c = gf * S.encc[tid] + gi * gg;
      float h = go * tanhx(c);
      S.encc[tid] = c;
      S.h4[tid] = h; S.c4[tid] = c;
    }
    __syncthreads();
    if (tid == 0){
      st4c(ws + HENC_OFF + (t & 1) * 1024 + 4 * w, S.h4);
      st4c(ws + CENC_OFF + 4 * w, S.c4);
    }
    ++ep; gbar(ws, ep, grp, &S.bail);

    // ============ R2: heads dhx/dcx + enc_score ============
    if (tid < 256){
      float4 v = ld4c(ws + HENC_OFF + (t & 1) * 1024 + tid * 4);
      *(float4*)&S.xs[tid * 4] = v;
    } else {
      float4 v = ld4c(ws + CENC_OFF + (tid - 256) * 4);
      *(float4*)&S.xs[1024 + (tid - 256) * 4] = v;
    }
    __syncthreads();
    if (hw < 4){
      float d = fmaxf(hw_dot<F32>(p.hxW, (long)(4 * w + hw) * 1024, S.xs, 1024, lane)
                      + S.hxb4[hw], 0.f);
      if (lane == 0) S.h4[hw] = d;
    } else if (hw < 8){
      int j = hw - 4;
      float d = fmaxf(hw_dot<F32>(p.cxW, (long)(4 * w + j) * 1024, S.xs + 1024, 1024, lane)
                      + S.cxb4[j], 0.f);
      if (lane == 0) S.dcx_s[j] = d;   // decoder c, reused by all 3 iters (ref bug)
    } else if (w >= 8 && w < 16){      // 8 WGs x 8 half-waves: enc_score
      int r = (w - 8) * 8 + (hw - 8);
      float s = hw_dot<F32>(p.clsW, (long)r * 1024, S.xs, 1024, lane) + S.clsb[r];
      if (lane == 0) stO<F32>(p.out, t * 64 + r, s);
    }
    __syncthreads();
    if (tid == 0) st4c(ws + DH_OFF + 4 * w, S.h4);
    ++ep; gbar(ws, ep, grp, &S.bail);

    // ============ R3: decoder iter 1 (fusion_in = 0) ============
    if (tid < 256){
      float4 v = ld4c(ws + DH_OFF + tid * 4);
      *(float4*)&S.xs[tid * 4] = v;
    }
    __syncthreads();
    {
      float a = lds_dot_bf16(S.decW + hw * 2048 + 1024, S.xs, 1024, lane) + S.bias_d[hw];
      if (lane == 0) S.g16[hw] = a;
    }
    __syncthreads();
    if (tid < 4){
      float gi = sigm(S.g16[tid]), gf = sigm(S.g16[4 + tid]),
            gg = tanhx(S.g16[8 + tid]), go = sigm(S.g16[12 + tid]);
      float c = gf * S.dcx_s[tid] + gi * gg;
      S.h4[tid] = go * tanhx(c);
    }
    __syncthreads();
    if (tid == 0) st4c(ws + DD_OFF + 1024 + 4 * w, S.h4);  // dh1 -> buf1
    if (tid < 64){                    // split-K partials -> PART1 (transposed)
      float sv = 0.f, fv = 0.f;
      #pragma unroll
      for (int j = 0; j < 4; ++j){
        sv = fmaf(S.cls_sl[tid * 4 + j], S.h4[j], sv);
        fv = fmaf(S.fut_sl[tid * 4 + j], S.h4[j], fv);
      }
      stg(ws + PART_OFF + 32768 + tid * 256 + w, sv);
      stg(ws + PART_OFF + 32768 + (64 + tid) * 256 + w, fv);
    }
    ++ep; gbar(ws, ep, grp, &S.bail);

    // ============ R4/R5: decoder iters 2,3 ============
    for (int di = 2; di <= 3; ++di){
      const int rb = (di - 1) & 1, wb = di & 1;
      if (tid < 256){
        float4 v = ld4c(ws + DD_OFF + rb * 1024 + tid * 4);
        *(float4*)&S.xs[1024 + tid * 4] = v;
      }
      reduce_parts(ws, rb, S, hw, lane);             // ds_{di-1}, fut_{di-1}
      __syncthreads();
      if (tid < 64){
        S.fut_acc[tid] += S.fv3[tid];
        if ((di == 2 && w == 16) || (di == 3 && w == 24))
          stO<F32>(p.out, TSTEPS * 64 + (t * 3 + (di - 2)) * 64 + tid, S.dsbuf[tid]);
      }
      {   // fusion_in = relu(fus_W @ ds + fus_b), per-thread 2 rows from VGPRs
        float a0 = fusb0, a1 = fusb1;
        #pragma unroll
        for (int o = 0; o < 64; ++o){
          float d = S.dsbuf[o];
          a0 = fmaf(bfu((u16t)(fw[o] & 0xffff)), d, a0);
          a1 = fmaf(bfu((u16t)(fw[o] >> 16)),    d, a1);
        }
        S.xs[2 * tid]     = fmaxf(a0, 0.f);
        S.xs[2 * tid + 1] = fmaxf(a1, 0.f);
      }
      __syncthreads();
      {
        float a = lds_dot_bf16(S.decW + hw * 2048, S.xs, 2048, lane) + S.bias_d[hw];
        if (lane == 0) S.g16[hw] = a;
      }
      __syncthreads();
      if (tid < 4){
        float gi = sigm(S.g16[tid]), gf = sigm(S.g16[4 + tid]),
              gg = tanhx(S.g16[8 + tid]), go = sigm(S.g16[12 + tid]);
        float c = gf * S.dcx_s[tid] + gi * gg;
        S.h4[tid] = go * tanhx(c);
      }
      __syncthreads();
      if (tid == 0) st4c(ws + DD_OFF + wb * 1024 + 4 * w, S.h4);
      if (tid < 64){
        float sv = 0.f, fv = 0.f;
        #pragma unroll
        for (int j = 0; j < 4; ++j){
          sv = fmaf(S.cls_sl[tid * 4 + j], S.h4[j], sv);
          fv = fmaf(S.fut_sl[tid * 4 + j], S.h4[j], fv);
        }
        stg(ws + PART_OFF + wb * 32768 + tid * 256 + w, sv);
        stg(ws + PART_OFF + wb * 32768 + (64 + tid) * 256 + w, fv);
      }
      ++ep; gbar(ws, ep, grp, &S.bail);
    }
  }

  // epilogue: ds3 of the final step (reduce PART1, WG 32 writes)
  if (w == 32){
    reduce_parts(ws, 1, S, hw, lane);
    __syncthreads();
    if (tid < 64)
      stO<F32>(p.out, TSTEPS * 64 + ((TSTEPS - 1) * 3 + 2) * 64 + tid, S.dsbuf[tid]);
  }
}

__global__ __launch_bounds__(NTHR, 2)
void trn_persist(Params p){
  __shared__ SharedMem S;
  // ---- runtime input-dtype detection from X's bit patterns ----
  if (threadIdx.x == 0){ S.bail = 0; S.badcnt = 0; }
  __syncthreads();
  if (threadIdx.x < 256){
    u16t u = ((const u16t*)p.X)[threadIdx.x];
    int e = (u >> 7) & 0xff;
    if (e == 0 || e >= 141) atomicAdd(&S.badcnt, 1);
  }
  __syncthreads();
  if (S.badcnt >= 3) run<true>(p, S);
  else               run<false>(p, S);
}

__global__ void ws_init(float* ws){
  int i = blockIdx.x * blockDim.x + threadIdx.x;
  if (i < WS_ZERO_N) ws[i] = 0.f;
}

extern "C" void kernel_launch(void* const* d_in, const int* in_sizes, int n_in,
                              void* d_out, int out_size, void* d_ws, size_t ws_size,
                              hipStream_t stream){
  Params P;
  P.X      = d_in[0];
  P.eWih   = d_in[1];
  P.eWhh   = d_in[2];
  P.ebih   = d_in[3];
  P.ebhh   = d_in[4];
  P.dWih   = d_in[5];
  P.dWhh   = d_in[6];
  P.dbih   = d_in[7];
  P.dbhh   = d_in[8];
  P.hxW    = d_in[9];
  P.hxb    = d_in[10];
  P.cxW    = d_in[11];
  P.cxb    = d_in[12];
  P.fusW   = d_in[13];
  P.fusb_g = d_in[14];
  P.futW   = d_in[15];
  P.futb_g = d_in[16];
  P.clsW   = d_in[17];
  P.clsb_g = d_in[18];
  P.ws     = (float*)d_ws;
  P.out    = d_out;

  ws_init<<<(WS_ZERO_N + 255) / 256, 256, 0, stream>>>(P.ws);

  void* args[] = { &P };
  hipLaunchCooperativeKernel((void*)trn_persist, dim3(NWG), dim3(NTHR),
                             args, 0, stream);
}

// Round 6
// 57427.325 us; speedup vs baseline: 2.4113x; 1.4443x over previous
//
#include <hip/hip_runtime.h>
#include <hip/hip_bf16.h>

// Persistent cooperative RNN kernel for MI355X (gfx950) — barrier-free
// epoch-tagged dataflow version.
// 256 WGs x 512 threads, 1 WG/CU (~151KB LDS). Each WG owns 4 hidden rows =>
// 16 gate rows of every 4H weight matrix. NO grid barriers: every cross-WG
// value is an 8-byte (f32 value, u32 epoch) pair written with an agent-scope
// 64-bit atomic store and consumed by polling coherent (sc0 sc1) 16B loads
// until the tag matches. Buffers are double-buffered by step parity; the 0xAA
// workspace poison never matches a tag, so no init kernel is needed.
// Small matvecs (cls/fut per decoder iter) use split-K partials reduced by 8
// dedicated WGs whose broadcast overlaps the other WGs' Whh dot.

typedef unsigned short u16t;
typedef unsigned int u32t;
typedef unsigned long long u64t;

#define TSTEPS 2045
#define NWG 256
#define NTHR 512
#define SPINCAP 8192

// d_ws float offsets (all pair arrays: 2 floats per element)
#define HENC  0        // [par][1024 pairs]  enc h
#define CENC  4096     // [par][1024 pairs]  enc c
#define DHX   8192     // [par][1024 pairs]  head dhx
#define DD1   12288    // [par][1024 pairs]  dec h1
#define DD2   16384    // [par][1024 pairs]  dec h2
#define SFF   20480    // [par][3 ph][128 pairs]   ds(0..63)|f(64..127)
#define PARTF 22016    // [par][3 ph][128 out][256 wg pairs]

struct Params {
  const void *X, *eWih, *eWhh, *ebih, *ebhh, *dWih, *dWhh, *dbih, *dbhh,
             *hxW, *hxb, *cxW, *cxb, *fusW, *fusb_g, *futW, *futb_g, *clsW, *clsb_g;
  float* ws;
  void* out;
};

struct SharedMem {
  alignas(16) float encW[16 * 1152];   // [row][Wih(128)|Whh(1024)] f32, 73728B
  alignas(16) u16t  decW[16 * 2048];   // [row][Wih(1024)|Whh(1024)] bf16, 65536B
  alignas(16) float xs[2048];          // staged vectors for dots
  float cls_sl[256], fut_sl[256];      // [o][j]: this WG's 4 columns
  float clsb[64], futb[64], fut_acc[64], dsbuf[64], fv3[64];
  float bias_e[16], bias_d[16], g16[16];
  float h4[4], dcx_s[4], encc[4], hxb4[4], cxb4[4];
  int bail;
  int badcnt;
};

__device__ __forceinline__ float bfu(u16t u){
  union { u32t i; float f; } v; v.i = ((u32t)u) << 16; return v.f;
}
__device__ __forceinline__ u32t fbits(float f){
  union { float f; u32t u; } c; c.f = f; return c.u;
}
__device__ __forceinline__ u16t bf16bits(float v){
  __hip_bfloat16 b = __float2bfloat16(v);
  union { __hip_bfloat16 b; u16t u; } c; c.b = b; return c.u;
}
template<bool F32>
__device__ __forceinline__ float ldE(const void* p, int i){
  if (F32) return ((const float*)p)[i];
  return bfu(((const u16t*)p)[i]);
}
template<bool F32>
__device__ __forceinline__ u16t ldB(const void* p, int i){
  if (F32) return bf16bits(((const float*)p)[i]);
  return ((const u16t*)p)[i];
}
template<bool F32>
__device__ __forceinline__ void stO(void* p, int i, float v){
  if (F32) ((float*)p)[i] = v;
  else     ((u16t*)p)[i] = bf16bits(v);
}
__device__ __forceinline__ float sigm(float x){ return 1.f / (1.f + __expf(-x)); }
__device__ __forceinline__ float tanhx(float x){
  float e = __expf(-2.f * fabsf(x));
  float t = (1.f - e) / (1.f + e);
  return copysignf(t, x);
}
// Tagged-pair store: (value, epoch) as one 64-bit agent-scope atomic.
__device__ __forceinline__ void stp(float* rowbase, int idx, float v, u32t ep){
  u64t u = (u64t)fbits(v) | ((u64t)ep << 32);
  __hip_atomic_store((u64t*)rowbase + idx, u,
                     __ATOMIC_RELAXED, __HIP_MEMORY_SCOPE_AGENT);
}
// Coherent 16B load (device coherence point).
__device__ __forceinline__ float4 ld4c(const float* p){
  float4 r;
  asm volatile("global_load_dwordx4 %0, %1, off sc0 sc1\n\t"
               "s_waitcnt vmcnt(0)"
               : "=&v"(r) : "v"(p) : "memory");
  return r;
}
// 4 coherent 16B loads, single wait.
__device__ __forceinline__ void ld4c4(const float* p0, const float* p1,
                                      const float* p2, const float* p3,
                                      float4& r0, float4& r1, float4& r2, float4& r3){
  asm volatile(
    "global_load_dwordx4 %0, %4, off sc0 sc1\n\t"
    "global_load_dwordx4 %1, %5, off sc0 sc1\n\t"
    "global_load_dwordx4 %2, %6, off sc0 sc1\n\t"
    "global_load_dwordx4 %3, %7, off sc0 sc1\n\t"
    "s_waitcnt vmcnt(0)"
    : "=&v"(r0), "=&v"(r1), "=&v"(r2), "=&v"(r3)
    : "v"(p0), "v"(p1), "v"(p2), "v"(p3)
    : "memory");
}
// Poll one quad (2 tagged pairs) until both tags == ep.
__device__ __forceinline__ float2 poll2(const float* q, u32t ep, int* bail){
  float4 r; int sp = 0;
  for (;;){
    r = ld4c(q);
    if (fbits(r.y) == ep && fbits(r.w) == ep) break;
    if (*bail) break;
    if (++sp > SPINCAP){ *bail = 1; break; }
  }
  return float2{r.x, r.z};
}

// Half-wave (32 lanes) dot of GLOBAL weight row with f32 x (LDS).
template<bool F32>
__device__ __forceinline__ float hw_dot(const void* wbase, long off,
                                        const float* __restrict__ x,
                                        int K, int lane){
  float acc = 0.f;
  if (F32){
    const float* w = (const float*)wbase + off;
    for (int c = lane * 4; c < K; c += 128){
      float4 wv = *(const float4*)(w + c);
      float4 xv = *(const float4*)(x + c);
      acc = fmaf(wv.x, xv.x, acc); acc = fmaf(wv.y, xv.y, acc);
      acc = fmaf(wv.z, xv.z, acc); acc = fmaf(wv.w, xv.w, acc);
    }
  } else {
    const u16t* w = (const u16t*)wbase + off;
    for (int c = lane * 4; c < K; c += 128){
      ushort4 wv = *(const ushort4*)(w + c);
      float4  xv = *(const float4*)(x + c);
      acc = fmaf(bfu(wv.x), xv.x, acc); acc = fmaf(bfu(wv.y), xv.y, acc);
      acc = fmaf(bfu(wv.z), xv.z, acc); acc = fmaf(bfu(wv.w), xv.w, acc);
    }
  }
  #pragma unroll
  for (int o = 16; o; o >>= 1) acc += __shfl_xor(acc, o, 64);
  return acc;
}

__device__ __forceinline__ float lds_dot_f32(const float* __restrict__ w,
                                             const float* __restrict__ x,
                                             int K, int lane){
  float acc = 0.f;
  for (int c = lane * 4; c < K; c += 128){
    float4 wv = *(const float4*)(w + c);
    float4 xv = *(const float4*)(x + c);
    acc = fmaf(wv.x, xv.x, acc); acc = fmaf(wv.y, xv.y, acc);
    acc = fmaf(wv.z, xv.z, acc); acc = fmaf(wv.w, xv.w, acc);
  }
  #pragma unroll
  for (int o = 16; o; o >>= 1) acc += __shfl_xor(acc, o, 64);
  return acc;
}

__device__ __forceinline__ float lds_dot_bf16(const u16t* __restrict__ w,
                                              const float* __restrict__ x,
                                              int K, int lane){
  float acc = 0.f;
  for (int c = lane * 8; c < K; c += 256){
    uint4  wv = *(const uint4*)(w + c);
    float4 x0 = *(const float4*)(x + c);
    float4 x1 = *(const float4*)(x + c + 4);
    acc = fmaf(bfu((u16t)(wv.x & 0xffff)), x0.x, acc);
    acc = fmaf(bfu((u16t)(wv.x >> 16)),    x0.y, acc);
    acc = fmaf(bfu((u16t)(wv.y & 0xffff)), x0.z, acc);
    acc = fmaf(bfu((u16t)(wv.y >> 16)),    x0.w, acc);
    acc = fmaf(bfu((u16t)(wv.z & 0xffff)), x1.x, acc);
    acc = fmaf(bfu((u16t)(wv.z >> 16)),    x1.y, acc);
    acc = fmaf(bfu((u16t)(wv.w & 0xffff)), x1.z, acc);
    acc = fmaf(bfu((u16t)(wv.w >> 16)),    x1.w, acc);
  }
  #pragma unroll
  for (int o = 16; o; o >>= 1) acc += __shfl_xor(acc, o, 64);
  return acc;
}

// Dedicated-WG reduction of one output's 256 split-K partials.
// o = (w&7)*16 + hw; lanes each poll 8 partial pairs, tree-sum in-wave.
// o<64: ds -> +clsb, write out[ds_ph], broadcast pair (ph<2).
// o>=64: f -> relu(+futb), broadcast pair.
template<bool F32>
__device__ __forceinline__ void reduce_phase(float* ws, int ph, int par, u32t ep,
                                             int t, SharedMem& S, void* out,
                                             int w, int hw, int lane){
  const int o = (w & 7) * 16 + hw;
  const float* row = ws + PARTF + (size_t)((par * 3 + ph) * 128 + o) * 512;
  const float* q = row + lane * 16;
  float4 r0, r1, r2, r3; int sp = 0;
  for (;;){
    ld4c4(q, q + 4, q + 8, q + 12, r0, r1, r2, r3);
    if (fbits(r0.y) == ep && fbits(r0.w) == ep && fbits(r1.y) == ep &&
        fbits(r1.w) == ep && fbits(r2.y) == ep && fbits(r2.w) == ep &&
        fbits(r3.y) == ep && fbits(r3.w) == ep) break;
    if (S.bail) break;
    if (++sp > SPINCAP){ S.bail = 1; break; }
  }
  float s = r0.x + r0.z + r1.x + r1.z + r2.x + r2.z + r3.x + r3.z;
  #pragma unroll
  for (int m = 16; m; m >>= 1) s += __shfl_xor(s, m, 64);
  if (lane == 0){
    float* sf = ws + SFF + (par * 3 + ph) * 256;
    if (o < 64){
      float v = s + S.clsb[o];
      stO<F32>(out, TSTEPS * 64 + (t * 3 + ph) * 64 + o, v);
      if (ph < 2) stp(sf, o, v, ep);
    } else {
      float v = fmaxf(s + S.futb[o - 64], 0.f);
      stp(sf, o, v, ep);
    }
  }
}

template<bool F32>
__device__ void run(const Params& p, SharedMem& S){
  const int tid  = threadIdx.x;
  const int w    = blockIdx.x;
  const int hw   = tid >> 5;            // half-wave 0..15 -> one gate row each
  const int lane = tid & 31;
  const long grow = (long)((hw >> 2) * 1024 + 4 * w + (hw & 3));  // gate row
  float* ws = p.ws;

  // ---------- startup: stage per-WG weights into LDS ----------
  {
    float* er = S.encW + hw * 1152;
    for (int c = lane; c < 128; c += 32)  er[c]       = ldE<F32>(p.eWih, (int)(grow * 128 + c));
    for (int c = lane; c < 1024; c += 32) er[128 + c] = ldE<F32>(p.eWhh, (int)(grow * 1024 + c));
    u16t* dr = S.decW + hw * 2048;
    for (int c = lane; c < 1024; c += 32){
      dr[c]        = ldB<F32>(p.dWih, (int)(grow * 1024 + c));
      dr[1024 + c] = ldB<F32>(p.dWhh, (int)(grow * 1024 + c));
    }
  }
  // fus_W rows for this thread's two h outputs -> registers
  u32t fw[64];
  float fusb0, fusb1;
  {
    int h0 = 2 * tid, h1 = 2 * tid + 1;
    #pragma unroll
    for (int o = 0; o < 64; ++o){
      u16t lo = ldB<F32>(p.fusW, h0 * 64 + o);
      u16t hi = ldB<F32>(p.fusW, h1 * 64 + o);
      fw[o] = ((u32t)hi << 16) | lo;
    }
    fusb0 = ldE<F32>(p.fusb_g, h0);
    fusb1 = ldE<F32>(p.fusb_g, h1);
  }
  if (tid < 256){
    int o = tid >> 2, j = tid & 3;
    S.cls_sl[tid] = ldE<F32>(p.clsW, o * 1024 + 4 * w + j);
    S.fut_sl[tid] = ldE<F32>(p.futW, o * 1024 + 4 * w + j);
  }
  if (tid < 64){
    S.clsb[tid] = ldE<F32>(p.clsb_g, tid);
    S.futb[tid] = ldE<F32>(p.futb_g, tid);
    S.fut_acc[tid] = 0.f;
  }
  if (tid < 16){
    int gr = (tid >> 2) * 1024 + 4 * w + (tid & 3);
    S.bias_e[tid] = ldE<F32>(p.ebih, gr) + ldE<F32>(p.ebhh, gr);
    S.bias_d[tid] = ldE<F32>(p.dbih, gr) + ldE<F32>(p.dbhh, gr);
  }
  if (tid < 4){
    S.hxb4[tid] = ldE<F32>(p.hxb, 4 * w + tid);
    S.cxb4[tid] = ldE<F32>(p.cxb, 4 * w + tid);
    S.encc[tid] = 0.f;
  }
  __syncthreads();

  for (int t = 0; t < TSTEPS; ++t){
    const int  par  = t & 1;
    const int  ppar = par ^ 1;
    const u32t ep   = (u32t)(t + 1);
    const u32t epv  = (u32t)t;            // tag of previous step's values

    // ============ R1: encoder gates ============
    if (t > 0){
      if (tid < 32){                       // f3 pairs: SF[ppar][ph2] quads 32..63
        const float* base = ws + SFF + (ppar * 3 + 2) * 256;
        float2 v = poll2(base + (32 + tid) * 4, epv, &S.bail);
        S.fv3[2 * tid] = v.x; S.fv3[2 * tid + 1] = v.y;
      }
      float2 v = poll2(ws + HENC + ppar * 2048 + tid * 4, epv, &S.bail);
      S.xs[128 + 2 * tid] = v.x; S.xs[129 + 2 * tid] = v.y;
    } else {
      S.xs[128 + 2 * tid] = 0.f; S.xs[129 + 2 * tid] = 0.f;
    }
    __syncthreads();
    if (tid < 64){
      S.xs[tid] = ldE<F32>(p.X, t * 64 + tid);         // fusion[0:64] = x_t
      float fv = (t > 0) ? (S.fut_acc[tid] + S.fv3[tid]) * (1.f / 3.f) : 0.f;
      S.xs[64 + tid] = fv;                             // fusion[64:128] = fut
      S.fut_acc[tid] = 0.f;
    }
    __syncthreads();
    {
      float a = lds_dot_f32(S.encW + hw * 1152, S.xs, 1152, lane) + S.bias_e[hw];
      if (lane == 0) S.g16[hw] = a;
    }
    __syncthreads();
    if (tid < 4){
      float gi = sigm(S.g16[tid]), gf = sigm(S.g16[4 + tid]),
            gg = tanhx(S.g16[8 + tid]), go = sigm(S.g16[12 + tid]);
      float c = gf * S.encc[tid] + gi * gg;
      float h = go * tanhx(c);
      S.encc[tid] = c;
      stp(ws + HENC + par * 2048, 4 * w + tid, h, ep);
      stp(ws + CENC + par * 2048, 4 * w + tid, c, ep);
    }

    // ============ R2: heads dhx/dcx + enc_score ============
    {
      float2 v = poll2(ws + HENC + par * 2048 + tid * 4, ep, &S.bail);
      S.xs[2 * tid] = v.x; S.xs[2 * tid + 1] = v.y;
      float2 c = poll2(ws + CENC + par * 2048 + tid * 4, ep, &S.bail);
      S.xs[1024 + 2 * tid] = c.x; S.xs[1025 + 2 * tid] = c.y;
    }
    __syncthreads();
    if (hw < 4){
      float d = fmaxf(hw_dot<F32>(p.hxW, (long)(4 * w + hw) * 1024, S.xs, 1024, lane)
                      + S.hxb4[hw], 0.f);
      if (lane == 0) stp(ws + DHX + par * 2048, 4 * w + hw, d, ep);
    } else if (hw < 8){
      int j = hw - 4;
      float d = fmaxf(hw_dot<F32>(p.cxW, (long)(4 * w + j) * 1024, S.xs + 1024, 1024, lane)
                      + S.cxb4[j], 0.f);
      if (lane == 0) S.dcx_s[j] = d;   // decoder c, reused by all 3 iters (ref bug)
    } else if (w >= 8 && w < 16){      // enc_score: 8 WGs x 8 half-waves
      int r = (w - 8) * 8 + (hw - 8);
      float s = hw_dot<F32>(p.clsW, (long)r * 1024, S.xs, 1024, lane) + S.clsb[r];
      if (lane == 0) stO<F32>(p.out, t * 64 + r, s);
    }

    // ============ R3: decoder iter 1 (fusion_in = 0) ============
    {
      float2 v = poll2(ws + DHX + par * 2048 + tid * 4, ep, &S.bail);
      S.xs[2 * tid] = v.x; S.xs[2 * tid + 1] = v.y;
    }
    __syncthreads();
    {
      float a = lds_dot_bf16(S.decW + hw * 2048 + 1024, S.xs, 1024, lane) + S.bias_d[hw];
      if (lane == 0) S.g16[hw] = a;
    }
    __syncthreads();
    if (tid < 4){
      float gi = sigm(S.g16[tid]), gf = sigm(S.g16[4 + tid]),
            gg = tanhx(S.g16[8 + tid]), go = sigm(S.g16[12 + tid]);
      float c = gf * S.dcx_s[tid] + gi * gg;
      float h = go * tanhx(c);
      S.h4[tid] = h;
      stp(ws + DD1 + par * 2048, 4 * w + tid, h, ep);
    }
    __syncthreads();
    if (tid < 64){                    // split-K partials (cls, fut) @ dh1 -> ph0
      float sv = 0.f, fv = 0.f;
      #pragma unroll
      for (int j = 0; j < 4; ++j){
        sv = fmaf(S.cls_sl[tid * 4 + j], S.h4[j], sv);
        fv = fmaf(S.fut_sl[tid * 4 + j], S.h4[j], fv);
      }
      float* base = ws + PARTF + (size_t)((par * 3 + 0) * 128) * 512;
      stp(base + (size_t)tid * 512,        w, sv, ep);
      stp(base + (size_t)(64 + tid) * 512, w, fv, ep);
    }

    // ============ R4/R5: decoder iters 2,3 ============
    for (int di = 2; di <= 3; ++di){
      const int ph = di - 2;               // partials produced in prev round
      // dedicated reducers for the just-produced partials
      if (w >= 16 + ph * 8 && w < 24 + ph * 8)
        reduce_phase<F32>(ws, ph, par, ep, t, S, p.out, w, hw, lane);
      // stage dh_{di-1} -> xs[1024:2048]
      {
        const float* dbuf = ws + (di == 2 ? DD1 : DD2) + par * 2048;
        float2 v = poll2(dbuf + tid * 4, ep, &S.bail);
        S.xs[1024 + 2 * tid] = v.x; S.xs[1025 + 2 * tid] = v.y;
      }
      __syncthreads();
      float accA = lds_dot_bf16(S.decW + hw * 2048 + 1024, S.xs + 1024, 1024, lane);
      // poll ds/f broadcast (produced by reducers, overlaps accA above)
      if (tid < 64){
        const float* sf = ws + SFF + (par * 3 + ph) * 256;
        float2 v = poll2(sf + tid * 4, ep, &S.bail);
        if (tid < 32){ S.dsbuf[2 * tid] = v.x; S.dsbuf[2 * tid + 1] = v.y; }
        else { S.fv3[2 * (tid - 32)] = v.x; S.fv3[2 * (tid - 32) + 1] = v.y; }
      }
      __syncthreads();
      if (tid < 64) S.fut_acc[tid] += S.fv3[tid];
      {   // fusion_in = relu(fus_W @ ds + fus_b), per-thread 2 rows from VGPRs
        float a0 = fusb0, a1 = fusb1;
        #pragma unroll
        for (int o = 0; o < 64; ++o){
          float d = S.dsbuf[o];
          a0 = fmaf(bfu((u16t)(fw[o] & 0xffff)), d, a0);
          a1 = fmaf(bfu((u16t)(fw[o] >> 16)),    d, a1);
        }
        S.xs[2 * tid]     = fmaxf(a0, 0.f);
        S.xs[2 * tid + 1] = fmaxf(a1, 0.f);
      }
      __syncthreads();
      float accB = lds_dot_bf16(S.decW + hw * 2048, S.xs, 1024, lane);
      {
        float a = accA + accB + S.bias_d[hw];
        if (lane == 0) S.g16[hw] = a;
      }
      __syncthreads();
      if (tid < 4){
        float gi = sigm(S.g16[tid]), gf = sigm(S.g16[4 + tid]),
              gg = tanhx(S.g16[8 + tid]), go = sigm(S.g16[12 + tid]);
        float c = gf * S.dcx_s[tid] + gi * gg;
        float h = go * tanhx(c);
        S.h4[tid] = h;
        if (di == 2) stp(ws + DD2 + par * 2048, 4 * w + tid, h, ep);
      }
      __syncthreads();
      if (tid < 64){                    // partials @ dh_di -> ph(di-1)
        float sv = 0.f, fv = 0.f;
        #pragma unroll
        for (int j = 0; j < 4; ++j){
          sv = fmaf(S.cls_sl[tid * 4 + j], S.h4[j], sv);
          fv = fmaf(S.fut_sl[tid * 4 + j], S.h4[j], fv);
        }
        float* base = ws + PARTF + (size_t)((par * 3 + di - 1) * 128) * 512;
        stp(base + (size_t)tid * 512,        w, sv, ep);
        stp(base + (size_t)(64 + tid) * 512, w, fv, ep);
      }
    }
    // ph2 reducers: produce ds3 (-> out) and f3 (-> next step's R1)
    if (w >= 32 && w < 40)
      reduce_phase<F32>(ws, 2, par, ep, t, S, p.out, w, hw, lane);
  }
}

__global__ __launch_bounds__(NTHR, 2)
void trn_persist(Params p){
  __shared__ SharedMem S;
  // ---- runtime input-dtype detection from X's bit patterns ----
  if (threadIdx.x == 0){ S.bail = 0; S.badcnt = 0; }
  __syncthreads();
  if (threadIdx.x < 256){
    u16t u = ((const u16t*)p.X)[threadIdx.x];
    int e = (u >> 7) & 0xff;
    if (e == 0 || e >= 141) atomicAdd(&S.badcnt, 1);
  }
  __syncthreads();
  if (S.badcnt >= 3) run<true>(p, S);
  else               run<false>(p, S);
}

extern "C" void kernel_launch(void* const* d_in, const int* in_sizes, int n_in,
                              void* d_out, int out_size, void* d_ws, size_t ws_size,
                              hipStream_t stream){
  Params P;
  P.X      = d_in[0];
  P.eWih   = d_in[1];
  P.eWhh   = d_in[2];
  P.ebih   = d_in[3];
  P.ebhh   = d_in[4];
  P.dWih   = d_in[5];
  P.dWhh   = d_in[6];
  P.dbih   = d_in[7];
  P.dbhh   = d_in[8];
  P.hxW    = d_in[9];
  P.hxb    = d_in[10];
  P.cxW    = d_in[11];
  P.cxb    = d_in[12];
  P.fusW   = d_in[13];
  P.fusb_g = d_in[14];
  P.futW   = d_in[15];
  P.futb_g = d_in[16];
  P.clsW   = d_in[17];
  P.clsb_g = d_in[18];
  P.ws     = (float*)d_ws;
  P.out    = d_out;

  void* args[] = { &P };
  hipLaunchCooperativeKernel((void*)trn_persist, dim3(NWG), dim3(NTHR),
                             args, 0, stream);
}